// Round 1
// baseline (2421.991 us; speedup 1.0000x reference)
//
#include <hip/hip_runtime.h>
#include <math.h>

namespace {

constexpr int B_ = 256;
constexpr int R_ = 1152;
constexpr int C_ = 10;
constexpr int O_ = 16;
constexpr int I_ = 8;
constexpr int CO_ = C_ * O_;          // 160
constexpr int WRI_ = C_ * O_ * I_;    // 1280 floats of W per route
constexpr int KS_ = 4;                // split-K factor over routes in k_s
constexpr int RCHUNK_ = R_ / KS_;     // 288 routes per block
constexpr int MB_ = 16;               // batch tile per block in k_s

__device__ __forceinline__ float squashf(float s) {
    // faithful to reference: s^2 * s / ((1+s^2)*sqrt(s^2)) == s*|s|/(1+s^2)
    return s * fabsf(s) / (1.0f + s * s);
}

// ---------------------------------------------------------------------------
// s[b,c,o] = sum_r cij[r,c] * sum_i W[r,c,o,i] * x[b,r,i]
// grid: (KS_, C_, B_/MB_); block: 256 = 16 o x 16 b
// accumulates via atomicAdd (s_out must be zeroed first)
// ---------------------------------------------------------------------------
template <bool UNIFORM>
__global__ __launch_bounds__(256) void k_s(const float* __restrict__ x,
                                           const float* __restrict__ Wm,
                                           const float* __restrict__ cij,
                                           float* __restrict__ s_out) {
    const int o  = threadIdx.x & 15;
    const int tb = threadIdx.x >> 4;               // 0..15
    const int b  = blockIdx.z * MB_ + tb;
    const int c  = blockIdx.y;
    const int r0 = blockIdx.x * RCHUNK_;

    const float* xp = x + ((size_t)b * R_ + r0) * I_;
    const float* wp = Wm + (((size_t)r0 * C_ + c) * O_ + o) * I_;
    const float* cp = cij + (size_t)r0 * C_ + c;   // unused when UNIFORM

    float acc = 0.f;
    #pragma unroll 4
    for (int r = 0; r < RCHUNK_; ++r) {
        const float4 xv0 = *(const float4*)(xp);
        const float4 xv1 = *(const float4*)(xp + 4);
        const float4 wv0 = *(const float4*)(wp);
        const float4 wv1 = *(const float4*)(wp + 4);
        float dot = xv0.x * wv0.x;
        dot = fmaf(xv0.y, wv0.y, dot);
        dot = fmaf(xv0.z, wv0.z, dot);
        dot = fmaf(xv0.w, wv0.w, dot);
        dot = fmaf(xv1.x, wv1.x, dot);
        dot = fmaf(xv1.y, wv1.y, dot);
        dot = fmaf(xv1.z, wv1.z, dot);
        dot = fmaf(xv1.w, wv1.w, dot);
        const float cw = UNIFORM ? (1.0f / (float)R_) : cp[0];
        acc = fmaf(cw, dot, acc);
        xp += I_;
        wp += WRI_;
        if (!UNIFORM) cp += C_;
    }
    atomicAdd(&s_out[((size_t)b * C_ + c) * O_ + o], acc);
}

// ---------------------------------------------------------------------------
// amean[r,c] = (1/B) * sum_b sum_o (sum_i W[r,c,o,i]*x[b,r,i]) * squash(s[b,c,o])
// grid: R_/2 blocks; block: 256 threads = one batch each; 2 routes per block
// ---------------------------------------------------------------------------
__global__ __launch_bounds__(256) void k_a(const float* __restrict__ x,
                                           const float* __restrict__ Wm,
                                           const float* __restrict__ s_in,
                                           float* __restrict__ amean) {
    __shared__ __align__(16) float wlds[2 * WRI_];   // 2560 floats = 10 KB
    __shared__ float red[4][2 * C_];

    const int tid = threadIdx.x;
    const int r0  = blockIdx.x * 2;

    // stage W for the two routes (contiguous 2560 floats)
    const float* wsrc = Wm + (size_t)r0 * WRI_;
    #pragma unroll
    for (int k = 0; k < 2 * WRI_ / 256; ++k)
        wlds[tid + 256 * k] = wsrc[tid + 256 * k];
    __syncthreads();

    const int b = tid;
    // x[b, r0+rr, 0:8]
    float xv[2][I_];
    const float4* xp4 = (const float4*)(x + ((size_t)b * R_ + r0) * I_);
    #pragma unroll
    for (int rr = 0; rr < 2; ++rr) {
        const float4 a0 = xp4[rr * 2 + 0];
        const float4 a1 = xp4[rr * 2 + 1];
        xv[rr][0] = a0.x; xv[rr][1] = a0.y; xv[rr][2] = a0.z; xv[rr][3] = a0.w;
        xv[rr][4] = a1.x; xv[rr][5] = a1.y; xv[rr][6] = a1.z; xv[rr][7] = a1.w;
    }

    float acc[2][C_];
    #pragma unroll
    for (int rr = 0; rr < 2; ++rr)
        #pragma unroll
        for (int c = 0; c < C_; ++c) acc[rr][c] = 0.f;

    #pragma unroll
    for (int c = 0; c < C_; ++c) {
        // v[b,c,o] = squash(s[b,c,o])
        const float4* sp4 = (const float4*)(s_in + ((size_t)b * C_ + c) * O_);
        float v[O_];
        #pragma unroll
        for (int q = 0; q < 4; ++q) {
            const float4 sv = sp4[q];
            v[q * 4 + 0] = squashf(sv.x);
            v[q * 4 + 1] = squashf(sv.y);
            v[q * 4 + 2] = squashf(sv.z);
            v[q * 4 + 3] = squashf(sv.w);
        }
        #pragma unroll
        for (int rr = 0; rr < 2; ++rr) {
            const float4* wl4 = (const float4*)&wlds[(rr * C_ + c) * O_ * I_];
            float a = 0.f;
            #pragma unroll
            for (int o = 0; o < O_; ++o) {
                const float4 w0 = wl4[o * 2 + 0];
                const float4 w1 = wl4[o * 2 + 1];
                float u = xv[rr][0] * w0.x;
                u = fmaf(xv[rr][1], w0.y, u);
                u = fmaf(xv[rr][2], w0.z, u);
                u = fmaf(xv[rr][3], w0.w, u);
                u = fmaf(xv[rr][4], w1.x, u);
                u = fmaf(xv[rr][5], w1.y, u);
                u = fmaf(xv[rr][6], w1.z, u);
                u = fmaf(xv[rr][7], w1.w, u);
                a = fmaf(u, v[o], a);
            }
            acc[rr][c] += a;
        }
    }

    // reduce 2*C_ values over 256 threads
    const int lane = tid & 63;
    const int wv   = tid >> 6;
    #pragma unroll
    for (int rr = 0; rr < 2; ++rr) {
        #pragma unroll
        for (int c = 0; c < C_; ++c) {
            float vsum = acc[rr][c];
            #pragma unroll
            for (int off = 32; off > 0; off >>= 1)
                vsum += __shfl_down(vsum, off, 64);
            if (lane == 0) red[wv][rr * C_ + c] = vsum;
        }
    }
    __syncthreads();
    if (tid < 2 * C_) {
        const float t = red[0][tid] + red[1][tid] + red[2][tid] + red[3][tid];
        const int rr = tid / C_;
        const int c  = tid % C_;
        amean[(size_t)(r0 + rr) * C_ + c] = t * (1.0f / (float)B_);
    }
}

// ---------------------------------------------------------------------------
// bij[r,c] += amean[r,c];  cij[r,c] = softmax over r (per capsule c)
// grid: C_ blocks of 256 threads
// ---------------------------------------------------------------------------
__global__ __launch_bounds__(256) void k_soft(const float* __restrict__ amean,
                                              float* __restrict__ bij,
                                              float* __restrict__ cij) {
    const int c   = blockIdx.x;
    const int tid = threadIdx.x;
    __shared__ float sred[4];

    float vals[5];
    float m = -1e30f;
    #pragma unroll
    for (int k = 0; k < 5; ++k) {
        const int r = tid + 256 * k;
        if (r < R_) {
            const size_t idx = (size_t)r * C_ + c;
            const float v = bij[idx] + amean[idx];
            bij[idx] = v;
            vals[k] = v;
            m = fmaxf(m, v);
        } else {
            vals[k] = -1e30f;
        }
    }
    #pragma unroll
    for (int off = 32; off > 0; off >>= 1)
        m = fmaxf(m, __shfl_down(m, off, 64));
    if ((tid & 63) == 0) sred[tid >> 6] = m;
    __syncthreads();
    const float bm = fmaxf(fmaxf(sred[0], sred[1]), fmaxf(sred[2], sred[3]));
    __syncthreads();

    float se = 0.f;
    #pragma unroll
    for (int k = 0; k < 5; ++k)
        se += (vals[k] > -1e29f) ? expf(vals[k] - bm) : 0.f;
    #pragma unroll
    for (int off = 32; off > 0; off >>= 1)
        se += __shfl_down(se, off, 64);
    if ((tid & 63) == 0) sred[tid >> 6] = se;
    __syncthreads();
    const float inv = 1.0f / (sred[0] + sred[1] + sred[2] + sred[3]);

    #pragma unroll
    for (int k = 0; k < 5; ++k) {
        const int r = tid + 256 * k;
        if (r < R_) cij[(size_t)r * C_ + c] = expf(vals[k] - bm) * inv;
    }
}

// ---------------------------------------------------------------------------
// in-place squash on final s (held in d_out)
// ---------------------------------------------------------------------------
__global__ __launch_bounds__(256) void k_squash(float* __restrict__ s) {
    const int idx = blockIdx.x * 256 + threadIdx.x;
    if (idx < B_ * CO_) s[idx] = squashf(s[idx]);
}

} // namespace

extern "C" void kernel_launch(void* const* d_in, const int* in_sizes, int n_in,
                              void* d_out, int out_size, void* d_ws, size_t ws_size,
                              hipStream_t stream) {
    const float* x  = (const float*)d_in[0];   // [256,1152,8]
    const float* Wm = (const float*)d_in[1];   // [1152,10,16,8]
    float* out = (float*)d_out;                // [256,10,16,1] flat = 40960
    float* ws  = (float*)d_ws;

    float* s_buf = ws;                 // 40960
    float* cij   = ws + 40960;         // 11520
    float* bij   = ws + 52480;         // 11520
    float* amean = ws + 64000;         // 11520

    const dim3 gs(KS_, C_, B_ / MB_);  // 4 x 10 x 16 = 640 blocks

    hipMemsetAsync(bij, 0, R_ * C_ * sizeof(float), stream);

    // ---- iter 0: uniform c_ij = 1/R ----
    hipMemsetAsync(s_buf, 0, B_ * CO_ * sizeof(float), stream);
    k_s<true><<<gs, 256, 0, stream>>>(x, Wm, cij, s_buf);
    k_a<<<R_ / 2, 256, 0, stream>>>(x, Wm, s_buf, amean);
    k_soft<<<C_, 256, 0, stream>>>(amean, bij, cij);

    // ---- iter 1 ----
    hipMemsetAsync(s_buf, 0, B_ * CO_ * sizeof(float), stream);
    k_s<false><<<gs, 256, 0, stream>>>(x, Wm, cij, s_buf);
    k_a<<<R_ / 2, 256, 0, stream>>>(x, Wm, s_buf, amean);
    k_soft<<<C_, 256, 0, stream>>>(amean, bij, cij);

    // ---- iter 2: final s into d_out, then squash in place ----
    hipMemsetAsync(out, 0, B_ * CO_ * sizeof(float), stream);
    k_s<false><<<gs, 256, 0, stream>>>(x, Wm, cij, out);
    k_squash<<<(B_ * CO_ + 255) / 256, 256, 0, stream>>>(out);
}

// Round 2
// 450.168 us; speedup vs baseline: 5.3802x; 5.3802x over previous
//
#include <hip/hip_runtime.h>
#include <math.h>

namespace {

constexpr int B_ = 256;
constexpr int R_ = 1152;
constexpr int C_ = 10;
constexpr int O_ = 16;
constexpr int I_ = 8;
constexpr int CO_ = C_ * O_;          // 160
constexpr int WRI_ = C_ * O_ * I_;    // 1280 floats of W per route
constexpr int KS_ = 4;                // split-K factor over routes in k_s
constexpr int RCHUNK_ = R_ / KS_;     // 288 routes per block
constexpr int MB_ = 16;               // batch tile per block in k_s

__device__ __forceinline__ float squashf(float s) {
    // faithful to reference: s^2 * s / ((1+s^2)*sqrt(s^2)) == s*|s|/(1+s^2)
    return s * fabsf(s) / (1.0f + s * s);
}

// ---------------------------------------------------------------------------
// s[b,c,o] = sum_r cij[r,c] * sum_i W[r,c,o,i] * x[b,r,i]
// grid: (KS_, C_, B_/MB_); block: 256 = 16 o x 16 b
// accumulates via atomicAdd (s_out must be zeroed first)
// ---------------------------------------------------------------------------
template <bool UNIFORM>
__global__ __launch_bounds__(256) void k_s(const float* __restrict__ x,
                                           const float* __restrict__ Wm,
                                           const float* __restrict__ cij,
                                           float* __restrict__ s_out) {
    const int o  = threadIdx.x & 15;
    const int tb = threadIdx.x >> 4;               // 0..15
    const int b  = blockIdx.z * MB_ + tb;
    const int c  = blockIdx.y;
    const int r0 = blockIdx.x * RCHUNK_;

    const float* xp = x + ((size_t)b * R_ + r0) * I_;
    const float* wp = Wm + (((size_t)r0 * C_ + c) * O_ + o) * I_;
    const float* cp = cij + (size_t)r0 * C_ + c;   // unused when UNIFORM

    float acc = 0.f;
    #pragma unroll 4
    for (int r = 0; r < RCHUNK_; ++r) {
        const float4 xv0 = *(const float4*)(xp);
        const float4 xv1 = *(const float4*)(xp + 4);
        const float4 wv0 = *(const float4*)(wp);
        const float4 wv1 = *(const float4*)(wp + 4);
        float dot = xv0.x * wv0.x;
        dot = fmaf(xv0.y, wv0.y, dot);
        dot = fmaf(xv0.z, wv0.z, dot);
        dot = fmaf(xv0.w, wv0.w, dot);
        dot = fmaf(xv1.x, wv1.x, dot);
        dot = fmaf(xv1.y, wv1.y, dot);
        dot = fmaf(xv1.z, wv1.z, dot);
        dot = fmaf(xv1.w, wv1.w, dot);
        const float cw = UNIFORM ? (1.0f / (float)R_) : cp[0];
        acc = fmaf(cw, dot, acc);
        xp += I_;
        wp += WRI_;
        if (!UNIFORM) cp += C_;
    }
    atomicAdd(&s_out[((size_t)b * C_ + c) * O_ + o], acc);
}

// ---------------------------------------------------------------------------
// amean[r,c] = (1/B) * sum_b sum_o (sum_i W[r,c,o,i]*x[b,r,i]) * squash(s[b,c,o])
// grid: R_/2 blocks; block: 256 threads = one batch each; 2 routes per block
// c-loop deliberately NOT unrolled; per-(c,rr) result is wave-reduced
// immediately (no runtime-indexed register arrays -> no scratch spills).
// ---------------------------------------------------------------------------
__global__ __launch_bounds__(256) void k_a(const float* __restrict__ x,
                                           const float* __restrict__ Wm,
                                           const float* __restrict__ s_in,
                                           float* __restrict__ amean) {
    __shared__ __align__(16) float wlds[2 * WRI_];   // 2560 floats = 10 KB
    __shared__ float red[4][2 * C_];

    const int tid = threadIdx.x;
    const int r0  = blockIdx.x * 2;

    // stage W for the two routes (contiguous 2560 floats)
    const float* wsrc = Wm + (size_t)r0 * WRI_;
    #pragma unroll
    for (int k = 0; k < 2 * WRI_ / 256; ++k)
        wlds[tid + 256 * k] = wsrc[tid + 256 * k];
    __syncthreads();

    const int b    = tid;
    const int lane = tid & 63;
    const int wv   = tid >> 6;

    // x[b, r0+rr, 0:8]
    float xv[2][I_];
    const float4* xp4 = (const float4*)(x + ((size_t)b * R_ + r0) * I_);
    #pragma unroll
    for (int rr = 0; rr < 2; ++rr) {
        const float4 a0 = xp4[rr * 2 + 0];
        const float4 a1 = xp4[rr * 2 + 1];
        xv[rr][0] = a0.x; xv[rr][1] = a0.y; xv[rr][2] = a0.z; xv[rr][3] = a0.w;
        xv[rr][4] = a1.x; xv[rr][5] = a1.y; xv[rr][6] = a1.z; xv[rr][7] = a1.w;
    }

    #pragma unroll 1
    for (int c = 0; c < C_; ++c) {
        // v[b,c,o] = squash(s[b,c,o])
        const float4* sp4 = (const float4*)(s_in + ((size_t)b * C_ + c) * O_);
        float v[O_];
        #pragma unroll
        for (int q = 0; q < 4; ++q) {
            const float4 sv = sp4[q];
            v[q * 4 + 0] = squashf(sv.x);
            v[q * 4 + 1] = squashf(sv.y);
            v[q * 4 + 2] = squashf(sv.z);
            v[q * 4 + 3] = squashf(sv.w);
        }
        #pragma unroll 1
        for (int rr = 0; rr < 2; ++rr) {
            const float4* wl4 = (const float4*)&wlds[(rr * C_ + c) * O_ * I_];
            float a = 0.f;
            #pragma unroll
            for (int o = 0; o < O_; ++o) {
                const float4 w0 = wl4[o * 2 + 0];
                const float4 w1 = wl4[o * 2 + 1];
                float u = xv[rr][0] * w0.x;
                u = fmaf(xv[rr][1], w0.y, u);
                u = fmaf(xv[rr][2], w0.z, u);
                u = fmaf(xv[rr][3], w0.w, u);
                u = fmaf(xv[rr][4], w1.x, u);
                u = fmaf(xv[rr][5], w1.y, u);
                u = fmaf(xv[rr][6], w1.z, u);
                u = fmaf(xv[rr][7], w1.w, u);
                a = fmaf(u, v[o], a);
            }
            // immediate wave reduction: no per-c register accumulator array
            #pragma unroll
            for (int off = 32; off > 0; off >>= 1)
                a += __shfl_down(a, off, 64);
            if (lane == 0) red[wv][rr * C_ + c] = a;
        }
    }

    __syncthreads();
    if (tid < 2 * C_) {
        const float t = red[0][tid] + red[1][tid] + red[2][tid] + red[3][tid];
        const int rr = tid / C_;
        const int c  = tid % C_;
        amean[(size_t)(r0 + rr) * C_ + c] = t * (1.0f / (float)B_);
    }
}

// ---------------------------------------------------------------------------
// bij[r,c] += amean[r,c];  cij[r,c] = softmax over r (per capsule c)
// grid: C_ blocks of 256 threads
// ---------------------------------------------------------------------------
__global__ __launch_bounds__(256) void k_soft(const float* __restrict__ amean,
                                              float* __restrict__ bij,
                                              float* __restrict__ cij) {
    const int c   = blockIdx.x;
    const int tid = threadIdx.x;
    __shared__ float sred[4];

    float vals[5];
    float m = -1e30f;
    #pragma unroll
    for (int k = 0; k < 5; ++k) {
        const int r = tid + 256 * k;
        if (r < R_) {
            const size_t idx = (size_t)r * C_ + c;
            const float v = bij[idx] + amean[idx];
            bij[idx] = v;
            vals[k] = v;
            m = fmaxf(m, v);
        } else {
            vals[k] = -1e30f;
        }
    }
    #pragma unroll
    for (int off = 32; off > 0; off >>= 1)
        m = fmaxf(m, __shfl_down(m, off, 64));
    if ((tid & 63) == 0) sred[tid >> 6] = m;
    __syncthreads();
    const float bm = fmaxf(fmaxf(sred[0], sred[1]), fmaxf(sred[2], sred[3]));
    __syncthreads();

    float se = 0.f;
    #pragma unroll
    for (int k = 0; k < 5; ++k)
        se += (vals[k] > -1e29f) ? expf(vals[k] - bm) : 0.f;
    #pragma unroll
    for (int off = 32; off > 0; off >>= 1)
        se += __shfl_down(se, off, 64);
    if ((tid & 63) == 0) sred[tid >> 6] = se;
    __syncthreads();
    const float inv = 1.0f / (sred[0] + sred[1] + sred[2] + sred[3]);

    #pragma unroll
    for (int k = 0; k < 5; ++k) {
        const int r = tid + 256 * k;
        if (r < R_) cij[(size_t)r * C_ + c] = expf(vals[k] - bm) * inv;
    }
}

// ---------------------------------------------------------------------------
// in-place squash on final s (held in d_out)
// ---------------------------------------------------------------------------
__global__ __launch_bounds__(256) void k_squash(float* __restrict__ s) {
    const int idx = blockIdx.x * 256 + threadIdx.x;
    if (idx < B_ * CO_) s[idx] = squashf(s[idx]);
}

} // namespace

extern "C" void kernel_launch(void* const* d_in, const int* in_sizes, int n_in,
                              void* d_out, int out_size, void* d_ws, size_t ws_size,
                              hipStream_t stream) {
    const float* x  = (const float*)d_in[0];   // [256,1152,8]
    const float* Wm = (const float*)d_in[1];   // [1152,10,16,8]
    float* out = (float*)d_out;                // [256,10,16,1] flat = 40960
    float* ws  = (float*)d_ws;

    float* s_buf = ws;                 // 40960
    float* cij   = ws + 40960;         // 11520
    float* bij   = ws + 52480;         // 11520
    float* amean = ws + 64000;         // 11520

    const dim3 gs(KS_, C_, B_ / MB_);  // 4 x 10 x 16 = 640 blocks

    hipMemsetAsync(bij, 0, R_ * C_ * sizeof(float), stream);

    // ---- iter 0: uniform c_ij = 1/R ----
    hipMemsetAsync(s_buf, 0, B_ * CO_ * sizeof(float), stream);
    k_s<true><<<gs, 256, 0, stream>>>(x, Wm, cij, s_buf);
    k_a<<<R_ / 2, 256, 0, stream>>>(x, Wm, s_buf, amean);
    k_soft<<<C_, 256, 0, stream>>>(amean, bij, cij);

    // ---- iter 1 ----
    hipMemsetAsync(s_buf, 0, B_ * CO_ * sizeof(float), stream);
    k_s<false><<<gs, 256, 0, stream>>>(x, Wm, cij, s_buf);
    k_a<<<R_ / 2, 256, 0, stream>>>(x, Wm, s_buf, amean);
    k_soft<<<C_, 256, 0, stream>>>(amean, bij, cij);

    // ---- iter 2: final s into d_out, then squash in place ----
    hipMemsetAsync(out, 0, B_ * CO_ * sizeof(float), stream);
    k_s<false><<<gs, 256, 0, stream>>>(x, Wm, cij, out);
    k_squash<<<(B_ * CO_ + 255) / 256, 256, 0, stream>>>(out);
}

// Round 3
// 242.005 us; speedup vs baseline: 10.0080x; 1.8602x over previous
//
#include <hip/hip_runtime.h>
#include <math.h>

namespace {

constexpr int B_ = 256;
constexpr int R_ = 1152;
constexpr int C_ = 10;
constexpr int O_ = 16;
constexpr int I_ = 8;
constexpr int CO_ = C_ * O_;          // 160
constexpr int WRI_ = C_ * O_ * I_;    // 1280 floats of W per route

// ---- fast path params ----
constexpr int KS2_ = 32;              // r-splits in k_s2
constexpr int RC2_ = R_ / KS2_;       // 36 routes per block

// ---- fallback path params (round-2 structure, KS bumped to 16) ----
constexpr int KSF_ = 16;
constexpr int RCF_ = R_ / KSF_;       // 72
constexpr int MBF_ = 16;

__device__ __forceinline__ float squashf(float s) {
    // faithful to reference: s^2*s/((1+s^2)*sqrt(s^2)) == s*|s|/(1+s^2)
    return s * fabsf(s) / (1.0f + s * s);
}

// ===========================================================================
// FAST PATH
// ===========================================================================

// x[b,r,i] -> xT[r,b,i].  tile: 8 b x 32 r.  grid 36*32=1152, 256 thr.
__global__ __launch_bounds__(256) void k_tr(const float* __restrict__ x,
                                            float* __restrict__ xT) {
    __shared__ float t[8][32][8];
    const int r0 = (blockIdx.x % 36) * 32;
    const int b0 = (blockIdx.x / 36) * 8;
    const int tid = threadIdx.x;
    {
        const int rl = tid & 31, bl = tid >> 5;
        const float4* p = (const float4*)(x + ((size_t)(b0 + bl) * R_ + (r0 + rl)) * I_);
        const float4 a0 = p[0], a1 = p[1];
        float* d = &t[bl][rl][0];
        *(float4*)d = a0;
        *(float4*)(d + 4) = a1;
    }
    __syncthreads();
    {
        const int f = tid & 7, rw = tid >> 3;   // f = b-local
        const float* s8 = &t[f][rw][0];
        const float4 a0 = *(const float4*)s8, a1 = *(const float4*)(s8 + 4);
        float* d = xT + ((size_t)(r0 + rw) * B_ + (b0 + f)) * I_;
        *(float4*)d = a0;
        *(float4*)(d + 4) = a1;
    }
}

// s_t[c,o,b] = sum_r cij[r,c] * dot(W[r,c,o,:], xT[r,b,:])
// grid (2, 10, KS2_), 256 thr = b.  W/cij wave-uniform -> scalar loads.
template <bool UNIFORM>
__global__ __launch_bounds__(256) void k_s2(const float* __restrict__ xT,
                                            const float* __restrict__ Wm,
                                            const float* __restrict__ cij,
                                            float* __restrict__ s_t) {
    const int b  = threadIdx.x;
    const int og = blockIdx.x;          // 0..1 (8 o's each)
    const int c  = blockIdx.y;          // 0..9
    const int r0 = blockIdx.z * RC2_;

    float acc[8];
    #pragma unroll
    for (int o = 0; o < 8; ++o) acc[o] = 0.f;

    const float* xp = xT + ((size_t)r0 * B_ + b) * I_;
    const float* wp = Wm + (((size_t)r0 * C_ + c) * O_ + og * 8) * I_;
    const float* cp = cij + (size_t)r0 * C_ + c;

    #pragma unroll 2
    for (int r = 0; r < RC2_; ++r) {
        const float4 xv0 = *(const float4*)xp;
        const float4 xv1 = *(const float4*)(xp + 4);
        const float cw = UNIFORM ? (1.0f / (float)R_) : cp[0];
        #pragma unroll
        for (int o = 0; o < 8; ++o) {
            const float4 w0 = *(const float4*)(wp + o * 8);
            const float4 w1 = *(const float4*)(wp + o * 8 + 4);
            const float p0 = fmaf(xv0.y, w0.y, xv0.x * w0.x);
            const float p1 = fmaf(xv0.w, w0.w, xv0.z * w0.z);
            const float p2 = fmaf(xv1.y, w1.y, xv1.x * w1.x);
            const float p3 = fmaf(xv1.w, w1.w, xv1.z * w1.z);
            acc[o] = fmaf(cw, (p0 + p1) + (p2 + p3), acc[o]);
        }
        xp += (size_t)B_ * I_;
        wp += WRI_;
        cp += C_;
    }

    float* sp = s_t + ((size_t)c * O_ + og * 8) * B_ + b;
    #pragma unroll
    for (int o = 0; o < 8; ++o) atomicAdd(sp + o * B_, acc[o]);
}

// v[b,co] = squash(s_t[co,b]).  grid CO_, 256 thr.
__global__ __launch_bounds__(256) void k_v(const float* __restrict__ s_t,
                                           float* __restrict__ v) {
    const int b  = threadIdx.x;
    const int co = blockIdx.x;
    v[(size_t)b * CO_ + co] = squashf(s_t[(size_t)co * B_ + b]);
}

// amean[r,c] = (1/B) sum_o sum_i W[r,c,o,i] * (sum_b v[b,c,o]*xT[r,b,i])
// grid R_, 192 thr (160 active co).  xT wave-uniform; v coalesced.
__global__ __launch_bounds__(192) void k_a2(const float* __restrict__ xT,
                                            const float* __restrict__ Wm,
                                            const float* __restrict__ v,
                                            float* __restrict__ amean) {
    const int co = threadIdx.x;
    const int r  = blockIdx.x;

    float acc[8];
    #pragma unroll
    for (int i = 0; i < 8; ++i) acc[i] = 0.f;

    if (co < CO_) {
        const float* xr = xT + (size_t)r * B_ * I_;
        const float* vp = v + co;
        #pragma unroll 4
        for (int b = 0; b < B_; ++b) {
            const float vt = vp[(size_t)b * CO_];
            const float4 x0 = *(const float4*)(xr + b * I_);
            const float4 x1 = *(const float4*)(xr + b * I_ + 4);
            acc[0] = fmaf(vt, x0.x, acc[0]);
            acc[1] = fmaf(vt, x0.y, acc[1]);
            acc[2] = fmaf(vt, x0.z, acc[2]);
            acc[3] = fmaf(vt, x0.w, acc[3]);
            acc[4] = fmaf(vt, x1.x, acc[4]);
            acc[5] = fmaf(vt, x1.y, acc[5]);
            acc[6] = fmaf(vt, x1.z, acc[6]);
            acc[7] = fmaf(vt, x1.w, acc[7]);
        }
    }

    float a = 0.f;
    if (co < CO_) {
        const float* wp = Wm + ((size_t)r * CO_ + co) * I_;
        const float4 w0 = *(const float4*)wp;
        const float4 w1 = *(const float4*)(wp + 4);
        const float p0 = fmaf(acc[1], w0.y, acc[0] * w0.x);
        const float p1 = fmaf(acc[3], w0.w, acc[2] * w0.z);
        const float p2 = fmaf(acc[5], w1.y, acc[4] * w1.x);
        const float p3 = fmaf(acc[7], w1.w, acc[6] * w1.z);
        a = (p0 + p1) + (p2 + p3);
    }
    #pragma unroll
    for (int off = 8; off > 0; off >>= 1) a += __shfl_down(a, off, 16);
    if (co < CO_ && (co & 15) == 0)
        amean[(size_t)r * C_ + (co >> 4)] = a * (1.0f / (float)B_);
}

// bij[r,c] += amean[r,c];  cij[r,c] = softmax over r.  grid C_, 256 thr.
__global__ __launch_bounds__(256) void k_soft(const float* __restrict__ amean,
                                              float* __restrict__ bij,
                                              float* __restrict__ cij) {
    const int c   = blockIdx.x;
    const int tid = threadIdx.x;
    __shared__ float sred[4];

    float vals[5];
    float m = -1e30f;
    #pragma unroll
    for (int k = 0; k < 5; ++k) {
        const int r = tid + 256 * k;
        if (r < R_) {
            const size_t idx = (size_t)r * C_ + c;
            const float vv = bij[idx] + amean[idx];
            bij[idx] = vv;
            vals[k] = vv;
            m = fmaxf(m, vv);
        } else {
            vals[k] = -1e30f;
        }
    }
    #pragma unroll
    for (int off = 32; off > 0; off >>= 1)
        m = fmaxf(m, __shfl_down(m, off, 64));
    if ((tid & 63) == 0) sred[tid >> 6] = m;
    __syncthreads();
    const float bm = fmaxf(fmaxf(sred[0], sred[1]), fmaxf(sred[2], sred[3]));
    __syncthreads();

    float se = 0.f;
    #pragma unroll
    for (int k = 0; k < 5; ++k)
        se += (vals[k] > -1e29f) ? expf(vals[k] - bm) : 0.f;
    #pragma unroll
    for (int off = 32; off > 0; off >>= 1)
        se += __shfl_down(se, off, 64);
    if ((tid & 63) == 0) sred[tid >> 6] = se;
    __syncthreads();
    const float inv = 1.0f / (sred[0] + sred[1] + sred[2] + sred[3]);

    #pragma unroll
    for (int k = 0; k < 5; ++k) {
        const int r = tid + 256 * k;
        if (r < R_) cij[(size_t)r * C_ + c] = expf(vals[k] - bm) * inv;
    }
}

// ===========================================================================
// FALLBACK PATH (round-2 structure; used only if ws is too small for xT)
// ===========================================================================

template <bool UNIFORM>
__global__ __launch_bounds__(256) void k_s_f(const float* __restrict__ x,
                                             const float* __restrict__ Wm,
                                             const float* __restrict__ cij,
                                             float* __restrict__ s_out) {
    const int o  = threadIdx.x & 15;
    const int tb = threadIdx.x >> 4;
    const int b  = blockIdx.z * MBF_ + tb;
    const int c  = blockIdx.y;
    const int r0 = blockIdx.x * RCF_;

    const float* xp = x + ((size_t)b * R_ + r0) * I_;
    const float* wp = Wm + (((size_t)r0 * C_ + c) * O_ + o) * I_;
    const float* cp = cij + (size_t)r0 * C_ + c;

    float acc = 0.f;
    #pragma unroll 4
    for (int r = 0; r < RCF_; ++r) {
        const float4 xv0 = *(const float4*)(xp);
        const float4 xv1 = *(const float4*)(xp + 4);
        const float4 wv0 = *(const float4*)(wp);
        const float4 wv1 = *(const float4*)(wp + 4);
        const float p0 = fmaf(xv0.y, wv0.y, xv0.x * wv0.x);
        const float p1 = fmaf(xv0.w, wv0.w, xv0.z * wv0.z);
        const float p2 = fmaf(xv1.y, wv1.y, xv1.x * wv1.x);
        const float p3 = fmaf(xv1.w, wv1.w, xv1.z * wv1.z);
        const float cw = UNIFORM ? (1.0f / (float)R_) : cp[0];
        acc = fmaf(cw, (p0 + p1) + (p2 + p3), acc);
        xp += I_;
        wp += WRI_;
        cp += C_;
    }
    atomicAdd(&s_out[((size_t)b * C_ + c) * O_ + o], acc);
}

__global__ __launch_bounds__(256) void k_a_f(const float* __restrict__ x,
                                             const float* __restrict__ Wm,
                                             const float* __restrict__ s_in,
                                             float* __restrict__ amean) {
    __shared__ __align__(16) float wlds[2 * WRI_];
    __shared__ float red[4][2 * C_];

    const int tid = threadIdx.x;
    const int r0  = blockIdx.x * 2;

    const float* wsrc = Wm + (size_t)r0 * WRI_;
    #pragma unroll
    for (int k = 0; k < 2 * WRI_ / 256; ++k)
        wlds[tid + 256 * k] = wsrc[tid + 256 * k];
    __syncthreads();

    const int b    = tid;
    const int lane = tid & 63;
    const int wv   = tid >> 6;

    float xv[2][I_];
    const float4* xp4 = (const float4*)(x + ((size_t)b * R_ + r0) * I_);
    #pragma unroll
    for (int rr = 0; rr < 2; ++rr) {
        const float4 a0 = xp4[rr * 2 + 0];
        const float4 a1 = xp4[rr * 2 + 1];
        xv[rr][0] = a0.x; xv[rr][1] = a0.y; xv[rr][2] = a0.z; xv[rr][3] = a0.w;
        xv[rr][4] = a1.x; xv[rr][5] = a1.y; xv[rr][6] = a1.z; xv[rr][7] = a1.w;
    }

    #pragma unroll 1
    for (int c = 0; c < C_; ++c) {
        const float4* sp4 = (const float4*)(s_in + ((size_t)b * C_ + c) * O_);
        float v[O_];
        #pragma unroll
        for (int q = 0; q < 4; ++q) {
            const float4 sv = sp4[q];
            v[q * 4 + 0] = squashf(sv.x);
            v[q * 4 + 1] = squashf(sv.y);
            v[q * 4 + 2] = squashf(sv.z);
            v[q * 4 + 3] = squashf(sv.w);
        }
        #pragma unroll 1
        for (int rr = 0; rr < 2; ++rr) {
            const float4* wl4 = (const float4*)&wlds[(rr * C_ + c) * O_ * I_];
            float a = 0.f;
            #pragma unroll
            for (int o = 0; o < O_; ++o) {
                const float4 w0 = wl4[o * 2 + 0];
                const float4 w1 = wl4[o * 2 + 1];
                float u = xv[rr][0] * w0.x;
                u = fmaf(xv[rr][1], w0.y, u);
                u = fmaf(xv[rr][2], w0.z, u);
                u = fmaf(xv[rr][3], w0.w, u);
                u = fmaf(xv[rr][4], w1.x, u);
                u = fmaf(xv[rr][5], w1.y, u);
                u = fmaf(xv[rr][6], w1.z, u);
                u = fmaf(xv[rr][7], w1.w, u);
                a = fmaf(u, v[o], a);
            }
            #pragma unroll
            for (int off = 32; off > 0; off >>= 1)
                a += __shfl_down(a, off, 64);
            if (lane == 0) red[wv][rr * C_ + c] = a;
        }
    }

    __syncthreads();
    if (tid < 2 * C_) {
        const float t = red[0][tid] + red[1][tid] + red[2][tid] + red[3][tid];
        const int rr = tid / C_;
        const int c  = tid % C_;
        amean[(size_t)(r0 + rr) * C_ + c] = t * (1.0f / (float)B_);
    }
}

__global__ __launch_bounds__(256) void k_squash(float* __restrict__ s) {
    const int idx = blockIdx.x * 256 + threadIdx.x;
    if (idx < B_ * CO_) s[idx] = squashf(s[idx]);
}

} // namespace

extern "C" void kernel_launch(void* const* d_in, const int* in_sizes, int n_in,
                              void* d_out, int out_size, void* d_ws, size_t ws_size,
                              hipStream_t stream) {
    const float* x  = (const float*)d_in[0];   // [256,1152,8]
    const float* Wm = (const float*)d_in[1];   // [1152,10,16,8]
    float* out = (float*)d_out;                // [256,10,16] flat = 40960
    float* ws  = (float*)d_ws;

    const size_t XT_N = (size_t)R_ * B_ * I_;  // 2,359,296 floats

    const size_t need_floats = XT_N + 2 * (size_t)(B_ * CO_) + 3 * (size_t)(R_ * C_);

    if (ws_size >= need_floats * sizeof(float)) {
        // ---------------- fast path ----------------
        float* xT    = ws;
        float* s_t   = xT + XT_N;                 // [CO_][B_]
        float* v     = s_t + B_ * CO_;            // [B_][CO_]
        float* cij   = v + B_ * CO_;              // [R_][C_]
        float* bij   = cij + R_ * C_;
        float* amean = bij + R_ * C_;

        k_tr<<<1152, 256, 0, stream>>>(x, xT);
        hipMemsetAsync(bij, 0, R_ * C_ * sizeof(float), stream);

        const dim3 gs(2, C_, KS2_);               // 640 blocks

        // iter 0
        hipMemsetAsync(s_t, 0, B_ * CO_ * sizeof(float), stream);
        k_s2<true><<<gs, 256, 0, stream>>>(xT, Wm, cij, s_t);
        k_v<<<CO_, B_, 0, stream>>>(s_t, v);
        k_a2<<<R_, 192, 0, stream>>>(xT, Wm, v, amean);
        k_soft<<<C_, 256, 0, stream>>>(amean, bij, cij);

        // iter 1
        hipMemsetAsync(s_t, 0, B_ * CO_ * sizeof(float), stream);
        k_s2<false><<<gs, 256, 0, stream>>>(xT, Wm, cij, s_t);
        k_v<<<CO_, B_, 0, stream>>>(s_t, v);
        k_a2<<<R_, 192, 0, stream>>>(xT, Wm, v, amean);
        k_soft<<<C_, 256, 0, stream>>>(amean, bij, cij);

        // iter 2: final v straight into d_out
        hipMemsetAsync(s_t, 0, B_ * CO_ * sizeof(float), stream);
        k_s2<false><<<gs, 256, 0, stream>>>(xT, Wm, cij, s_t);
        k_v<<<CO_, B_, 0, stream>>>(s_t, out);
    } else {
        // ---------------- fallback (round-2 pipeline) ----------------
        float* s_buf = ws;                 // 40960
        float* cij   = ws + 40960;
        float* bij   = cij + R_ * C_;
        float* amean = bij + R_ * C_;

        const dim3 gs(KSF_, C_, B_ / MBF_);

        hipMemsetAsync(bij, 0, R_ * C_ * sizeof(float), stream);

        hipMemsetAsync(s_buf, 0, B_ * CO_ * sizeof(float), stream);
        k_s_f<true><<<gs, 256, 0, stream>>>(x, Wm, cij, s_buf);
        k_a_f<<<R_ / 2, 256, 0, stream>>>(x, Wm, s_buf, amean);
        k_soft<<<C_, 256, 0, stream>>>(amean, bij, cij);

        hipMemsetAsync(s_buf, 0, B_ * CO_ * sizeof(float), stream);
        k_s_f<false><<<gs, 256, 0, stream>>>(x, Wm, cij, s_buf);
        k_a_f<<<R_ / 2, 256, 0, stream>>>(x, Wm, s_buf, amean);
        k_soft<<<C_, 256, 0, stream>>>(amean, bij, cij);

        hipMemsetAsync(out, 0, B_ * CO_ * sizeof(float), stream);
        k_s_f<false><<<gs, 256, 0, stream>>>(x, Wm, cij, out);
        k_squash<<<(B_ * CO_ + 255) / 256, 256, 0, stream>>>(out);
    }
}

// Round 4
// 217.391 us; speedup vs baseline: 11.1412x; 1.1132x over previous
//
#include <hip/hip_runtime.h>
#include <math.h>

namespace {

constexpr int B_ = 256;
constexpr int R_ = 1152;
constexpr int C_ = 10;
constexpr int O_ = 16;
constexpr int I_ = 8;
constexpr int CO_ = C_ * O_;          // 160
constexpr int WRI_ = C_ * O_ * I_;    // 1280 floats of W per route

// ---- fast path params ----
constexpr int KS2_ = 64;              // r-splits in k_s2
constexpr int RC2_ = R_ / KS2_;       // 18 routes per block

// ---- fallback path params ----
constexpr int KSF_ = 16;
constexpr int RCF_ = R_ / KSF_;       // 72
constexpr int MBF_ = 16;

__device__ __forceinline__ float squashf(float s) {
    // faithful to reference: s^2*s/((1+s^2)*sqrt(s^2)) == s*|s|/(1+s^2)
    return s * fabsf(s) / (1.0f + s * s);
}

// ===========================================================================
// FAST PATH
// ===========================================================================

// x[b,r,i] -> xT[r,b,i].  tile: 8 b x 32 r.  grid 36*32=1152, 256 thr.
__global__ __launch_bounds__(256) void k_tr(const float* __restrict__ x,
                                            float* __restrict__ xT) {
    __shared__ float t[8][32][8];
    const int r0 = (blockIdx.x % 36) * 32;
    const int b0 = (blockIdx.x / 36) * 8;
    const int tid = threadIdx.x;
    {
        const int rl = tid & 31, bl = tid >> 5;
        const float4* p = (const float4*)(x + ((size_t)(b0 + bl) * R_ + (r0 + rl)) * I_);
        const float4 a0 = p[0], a1 = p[1];
        float* d = &t[bl][rl][0];
        *(float4*)d = a0;
        *(float4*)(d + 4) = a1;
    }
    __syncthreads();
    {
        const int f = tid & 7, rw = tid >> 3;   // f = b-local
        const float* s8 = &t[f][rw][0];
        const float4 a0 = *(const float4*)s8, a1 = *(const float4*)(s8 + 4);
        float* d = xT + ((size_t)(r0 + rw) * B_ + (b0 + f)) * I_;
        *(float4*)d = a0;
        *(float4*)(d + 4) = a1;
    }
}

// s_t[c,o,b] += sum_r cij[r,c] * dot(W[r,c,o,:], xT[r,b,:])
// grid (2, 10, KS2_), 256 thr = b.  W/cij wave-uniform -> scalar loads.
// x / cij for r+1 software-pipelined one iteration ahead.
template <bool UNIFORM>
__global__ __launch_bounds__(256) void k_s2(const float* __restrict__ xT,
                                            const float* __restrict__ Wm,
                                            const float* __restrict__ cij,
                                            float* __restrict__ s_t) {
    const int b  = threadIdx.x;
    const int og = blockIdx.x;          // 0..1 (8 o's each)
    const int c  = blockIdx.y;          // 0..9
    const int r0 = blockIdx.z * RC2_;

    float acc[8];
    #pragma unroll
    for (int o = 0; o < 8; ++o) acc[o] = 0.f;

    const float4* xp4 = (const float4*)(xT + ((size_t)r0 * B_ + b) * I_);
    const float*  wp  = Wm + (((size_t)r0 * C_ + c) * O_ + og * 8) * I_;
    const float*  cp  = cij + (size_t)r0 * C_ + c;

    float4 x0 = xp4[0], x1 = xp4[1];
    float  cw = UNIFORM ? (1.0f / (float)R_) : cp[0];

    #pragma unroll 1
    for (int r = 0; r < RC2_; ++r) {
        const float4 cx0 = x0, cx1 = x1;
        const float  ccw = cw;
        if (r + 1 < RC2_) {                       // prefetch next r
            xp4 += (B_ * I_) / 4;
            x0 = xp4[0];
            x1 = xp4[1];
            if (!UNIFORM) { cp += C_; cw = cp[0]; }
        }
        #pragma unroll
        for (int o = 0; o < 8; ++o) {
            const float4 w0 = *(const float4*)(wp + o * 8);
            const float4 w1 = *(const float4*)(wp + o * 8 + 4);
            const float p0 = fmaf(cx0.y, w0.y, cx0.x * w0.x);
            const float p1 = fmaf(cx0.w, w0.w, cx0.z * w0.z);
            const float p2 = fmaf(cx1.y, w1.y, cx1.x * w1.x);
            const float p3 = fmaf(cx1.w, w1.w, cx1.z * w1.z);
            acc[o] = fmaf(ccw, (p0 + p1) + (p2 + p3), acc[o]);
        }
        wp += WRI_;
    }

    float* sp = s_t + ((size_t)c * O_ + og * 8) * B_ + b;
    #pragma unroll
    for (int o = 0; o < 8; ++o) atomicAdd(sp + o * B_, acc[o]);
}

// v[b,co] = squash(s_t[co,b]); optionally zero s_t for the next iteration
// (replaces a memset node).  grid CO_, 256 thr.
template <bool CLEAR>
__global__ __launch_bounds__(256) void k_v(float* __restrict__ s_t,
                                           float* __restrict__ v) {
    const int b  = threadIdx.x;
    const int co = blockIdx.x;
    const size_t si = (size_t)co * B_ + b;
    v[(size_t)b * CO_ + co] = squashf(s_t[si]);
    if (CLEAR) s_t[si] = 0.f;
}

// amean[r,c] = (1/B) sum_o sum_i W[r,c,o,i] * (sum_b v[b,c,o]*xT[r,b,i])
// grid R_ blocks, 640 thr = 160 co x 4 b-groups of 64.
// xT row staged in LDS (broadcast reads); v coalesced; 64 iters/thread.
__global__ __launch_bounds__(640) void k_a3(const float* __restrict__ xT,
                                            const float* __restrict__ Wm,
                                            const float* __restrict__ v,
                                            float* __restrict__ amean) {
    __shared__ __align__(16) float xrow[B_ * I_];   // 8 KB
    __shared__ float part[640];

    const int tid = threadIdx.x;
    const int r   = blockIdx.x;

    if (tid < (B_ * I_) / 4)
        ((float4*)xrow)[tid] = ((const float4*)(xT + (size_t)r * B_ * I_))[tid];
    __syncthreads();

    const int co = tid % CO_;
    const int bg = tid / CO_;           // 0..3
    const int b0 = bg * 64;

    float acc[8];
    #pragma unroll
    for (int i = 0; i < 8; ++i) acc[i] = 0.f;

    const float* vp = v + co;
    #pragma unroll 4
    for (int bb = 0; bb < 64; ++bb) {
        const int b = b0 + bb;
        const float vt = vp[(size_t)b * CO_];
        const float4 y0 = *(const float4*)(&xrow[b * I_]);
        const float4 y1 = *(const float4*)(&xrow[b * I_ + 4]);
        acc[0] = fmaf(vt, y0.x, acc[0]);
        acc[1] = fmaf(vt, y0.y, acc[1]);
        acc[2] = fmaf(vt, y0.z, acc[2]);
        acc[3] = fmaf(vt, y0.w, acc[3]);
        acc[4] = fmaf(vt, y1.x, acc[4]);
        acc[5] = fmaf(vt, y1.y, acc[5]);
        acc[6] = fmaf(vt, y1.z, acc[6]);
        acc[7] = fmaf(vt, y1.w, acc[7]);
    }

    // dot with W[r,co,:]
    {
        const float* wp = Wm + ((size_t)r * CO_ + co) * I_;
        const float4 w0 = *(const float4*)wp;
        const float4 w1 = *(const float4*)(wp + 4);
        const float p0 = fmaf(acc[1], w0.y, acc[0] * w0.x);
        const float p1 = fmaf(acc[3], w0.w, acc[2] * w0.z);
        const float p2 = fmaf(acc[5], w1.y, acc[4] * w1.x);
        const float p3 = fmaf(acc[7], w1.w, acc[6] * w1.z);
        part[tid] = (p0 + p1) + (p2 + p3);
    }
    __syncthreads();

    if (tid < CO_) {
        float a = part[tid] + part[CO_ + tid] + part[2 * CO_ + tid] + part[3 * CO_ + tid];
        #pragma unroll
        for (int off = 8; off > 0; off >>= 1)
            a += __shfl_down(a, off, 16);
        if ((tid & 15) == 0)
            amean[(size_t)r * C_ + (tid >> 4)] = a * (1.0f / (float)B_);
    }
}

// bij[r,c] += amean[r,c];  cij[r,c] = softmax over r.  grid C_, 256 thr.
__global__ __launch_bounds__(256) void k_soft(const float* __restrict__ amean,
                                              float* __restrict__ bij,
                                              float* __restrict__ cij) {
    const int c   = blockIdx.x;
    const int tid = threadIdx.x;
    __shared__ float sred[4];

    float vals[5];
    float m = -1e30f;
    #pragma unroll
    for (int k = 0; k < 5; ++k) {
        const int r = tid + 256 * k;
        if (r < R_) {
            const size_t idx = (size_t)r * C_ + c;
            const float vv = bij[idx] + amean[idx];
            bij[idx] = vv;
            vals[k] = vv;
            m = fmaxf(m, vv);
        } else {
            vals[k] = -1e30f;
        }
    }
    #pragma unroll
    for (int off = 32; off > 0; off >>= 1)
        m = fmaxf(m, __shfl_down(m, off, 64));
    if ((tid & 63) == 0) sred[tid >> 6] = m;
    __syncthreads();
    const float bm = fmaxf(fmaxf(sred[0], sred[1]), fmaxf(sred[2], sred[3]));
    __syncthreads();

    float se = 0.f;
    #pragma unroll
    for (int k = 0; k < 5; ++k)
        se += (vals[k] > -1e29f) ? expf(vals[k] - bm) : 0.f;
    #pragma unroll
    for (int off = 32; off > 0; off >>= 1)
        se += __shfl_down(se, off, 64);
    if ((tid & 63) == 0) sred[tid >> 6] = se;
    __syncthreads();
    const float inv = 1.0f / (sred[0] + sred[1] + sred[2] + sred[3]);

    #pragma unroll
    for (int k = 0; k < 5; ++k) {
        const int r = tid + 256 * k;
        if (r < R_) cij[(size_t)r * C_ + c] = expf(vals[k] - bm) * inv;
    }
}

// ===========================================================================
// FALLBACK PATH (used only if ws is too small for xT)
// ===========================================================================

template <bool UNIFORM>
__global__ __launch_bounds__(256) void k_s_f(const float* __restrict__ x,
                                             const float* __restrict__ Wm,
                                             const float* __restrict__ cij,
                                             float* __restrict__ s_out) {
    const int o  = threadIdx.x & 15;
    const int tb = threadIdx.x >> 4;
    const int b  = blockIdx.z * MBF_ + tb;
    const int c  = blockIdx.y;
    const int r0 = blockIdx.x * RCF_;

    const float* xp = x + ((size_t)b * R_ + r0) * I_;
    const float* wp = Wm + (((size_t)r0 * C_ + c) * O_ + o) * I_;
    const float* cp = cij + (size_t)r0 * C_ + c;

    float acc = 0.f;
    #pragma unroll 4
    for (int r = 0; r < RCF_; ++r) {
        const float4 xv0 = *(const float4*)(xp);
        const float4 xv1 = *(const float4*)(xp + 4);
        const float4 wv0 = *(const float4*)(wp);
        const float4 wv1 = *(const float4*)(wp + 4);
        const float p0 = fmaf(xv0.y, wv0.y, xv0.x * wv0.x);
        const float p1 = fmaf(xv0.w, wv0.w, xv0.z * wv0.z);
        const float p2 = fmaf(xv1.y, wv1.y, xv1.x * wv1.x);
        const float p3 = fmaf(xv1.w, wv1.w, xv1.z * wv1.z);
        const float cw = UNIFORM ? (1.0f / (float)R_) : cp[0];
        acc = fmaf(cw, (p0 + p1) + (p2 + p3), acc);
        xp += I_;
        wp += WRI_;
        cp += C_;
    }
    atomicAdd(&s_out[((size_t)b * C_ + c) * O_ + o], acc);
}

__global__ __launch_bounds__(256) void k_a_f(const float* __restrict__ x,
                                             const float* __restrict__ Wm,
                                             const float* __restrict__ s_in,
                                             float* __restrict__ amean) {
    __shared__ __align__(16) float wlds[2 * WRI_];
    __shared__ float red[4][2 * C_];

    const int tid = threadIdx.x;
    const int r0  = blockIdx.x * 2;

    const float* wsrc = Wm + (size_t)r0 * WRI_;
    #pragma unroll
    for (int k = 0; k < 2 * WRI_ / 256; ++k)
        wlds[tid + 256 * k] = wsrc[tid + 256 * k];
    __syncthreads();

    const int b    = tid;
    const int lane = tid & 63;
    const int wv   = tid >> 6;

    float xv[2][I_];
    const float4* xp4 = (const float4*)(x + ((size_t)b * R_ + r0) * I_);
    #pragma unroll
    for (int rr = 0; rr < 2; ++rr) {
        const float4 a0 = xp4[rr * 2 + 0];
        const float4 a1 = xp4[rr * 2 + 1];
        xv[rr][0] = a0.x; xv[rr][1] = a0.y; xv[rr][2] = a0.z; xv[rr][3] = a0.w;
        xv[rr][4] = a1.x; xv[rr][5] = a1.y; xv[rr][6] = a1.z; xv[rr][7] = a1.w;
    }

    #pragma unroll 1
    for (int c = 0; c < C_; ++c) {
        const float4* sp4 = (const float4*)(s_in + ((size_t)b * C_ + c) * O_);
        float v[O_];
        #pragma unroll
        for (int q = 0; q < 4; ++q) {
            const float4 sv = sp4[q];
            v[q * 4 + 0] = squashf(sv.x);
            v[q * 4 + 1] = squashf(sv.y);
            v[q * 4 + 2] = squashf(sv.z);
            v[q * 4 + 3] = squashf(sv.w);
        }
        #pragma unroll 1
        for (int rr = 0; rr < 2; ++rr) {
            const float4* wl4 = (const float4*)&wlds[(rr * C_ + c) * O_ * I_];
            float a = 0.f;
            #pragma unroll
            for (int o = 0; o < O_; ++o) {
                const float4 w0 = wl4[o * 2 + 0];
                const float4 w1 = wl4[o * 2 + 1];
                float u = xv[rr][0] * w0.x;
                u = fmaf(xv[rr][1], w0.y, u);
                u = fmaf(xv[rr][2], w0.z, u);
                u = fmaf(xv[rr][3], w0.w, u);
                u = fmaf(xv[rr][4], w1.x, u);
                u = fmaf(xv[rr][5], w1.y, u);
                u = fmaf(xv[rr][6], w1.z, u);
                u = fmaf(xv[rr][7], w1.w, u);
                a = fmaf(u, v[o], a);
            }
            #pragma unroll
            for (int off = 32; off > 0; off >>= 1)
                a += __shfl_down(a, off, 64);
            if (lane == 0) red[wv][rr * C_ + c] = a;
        }
    }

    __syncthreads();
    if (tid < 2 * C_) {
        const float t = red[0][tid] + red[1][tid] + red[2][tid] + red[3][tid];
        const int rr = tid / C_;
        const int c  = tid % C_;
        amean[(size_t)(r0 + rr) * C_ + c] = t * (1.0f / (float)B_);
    }
}

__global__ __launch_bounds__(256) void k_squash(float* __restrict__ s) {
    const int idx = blockIdx.x * 256 + threadIdx.x;
    if (idx < B_ * CO_) s[idx] = squashf(s[idx]);
}

} // namespace

extern "C" void kernel_launch(void* const* d_in, const int* in_sizes, int n_in,
                              void* d_out, int out_size, void* d_ws, size_t ws_size,
                              hipStream_t stream) {
    const float* x  = (const float*)d_in[0];   // [256,1152,8]
    const float* Wm = (const float*)d_in[1];   // [1152,10,16,8]
    float* out = (float*)d_out;                // [256,10,16] flat = 40960
    float* ws  = (float*)d_ws;

    const size_t XT_N = (size_t)R_ * B_ * I_;  // 2,359,296 floats
    const size_t need_floats = XT_N + 2 * (size_t)(B_ * CO_) + 3 * (size_t)(R_ * C_);

    if (ws_size >= need_floats * sizeof(float)) {
        // ---------------- fast path ----------------
        float* xT    = ws;
        float* s_t   = xT + XT_N;                 // [CO_][B_]
        float* v     = s_t + B_ * CO_;            // [B_][CO_]
        float* cij   = v + B_ * CO_;              // [R_][C_]
        float* bij   = cij + R_ * C_;
        float* amean = bij + R_ * C_;

        k_tr<<<1152, 256, 0, stream>>>(x, xT);
        hipMemsetAsync(bij, 0, R_ * C_ * sizeof(float), stream);
        hipMemsetAsync(s_t, 0, B_ * CO_ * sizeof(float), stream);

        const dim3 gs(2, C_, KS2_);               // 1280 blocks

        // iter 0
        k_s2<true><<<gs, 256, 0, stream>>>(xT, Wm, cij, s_t);
        k_v<true><<<CO_, B_, 0, stream>>>(s_t, v);   // also zeroes s_t
        k_a3<<<R_, 640, 0, stream>>>(xT, Wm, v, amean);
        k_soft<<<C_, 256, 0, stream>>>(amean, bij, cij);

        // iter 1
        k_s2<false><<<gs, 256, 0, stream>>>(xT, Wm, cij, s_t);
        k_v<true><<<CO_, B_, 0, stream>>>(s_t, v);   // also zeroes s_t
        k_a3<<<R_, 640, 0, stream>>>(xT, Wm, v, amean);
        k_soft<<<C_, 256, 0, stream>>>(amean, bij, cij);

        // iter 2: final v straight into d_out
        k_s2<false><<<gs, 256, 0, stream>>>(xT, Wm, cij, s_t);
        k_v<false><<<CO_, B_, 0, stream>>>(s_t, out);
    } else {
        // ---------------- fallback ----------------
        float* s_buf = ws;
        float* cij   = ws + 40960;
        float* bij   = cij + R_ * C_;
        float* amean = bij + R_ * C_;

        const dim3 gs(KSF_, C_, B_ / MBF_);

        hipMemsetAsync(bij, 0, R_ * C_ * sizeof(float), stream);

        hipMemsetAsync(s_buf, 0, B_ * CO_ * sizeof(float), stream);
        k_s_f<true><<<gs, 256, 0, stream>>>(x, Wm, cij, s_buf);
        k_a_f<<<R_ / 2, 256, 0, stream>>>(x, Wm, s_buf, amean);
        k_soft<<<C_, 256, 0, stream>>>(amean, bij, cij);

        hipMemsetAsync(s_buf, 0, B_ * CO_ * sizeof(float), stream);
        k_s_f<false><<<gs, 256, 0, stream>>>(x, Wm, cij, s_buf);
        k_a_f<<<R_ / 2, 256, 0, stream>>>(x, Wm, s_buf, amean);
        k_soft<<<C_, 256, 0, stream>>>(amean, bij, cij);

        hipMemsetAsync(out, 0, B_ * CO_ * sizeof(float), stream);
        k_s_f<false><<<gs, 256, 0, stream>>>(x, Wm, cij, out);
        k_squash<<<(B_ * CO_ + 255) / 256, 256, 0, stream>>>(out);
    }
}